// Round 15
// baseline (444.253 us; speedup 1.0000x reference)
//
#include <hip/hip_runtime.h>
#include <hip/hip_bf16.h>
#include <stdint.h>

// Spatial local attention, MI355X bf16-MFMA implementation.
// Round 15: (a) out_conv widened to 8 waves (512 thr), halved per-wave serial chain;
// (b) pv_gemm exp-transform sandwiched between MFMA halves (off the phase tail).
// qk/qkv/transpose/row_stats unchanged from round 14.
//
// Workspace layout (bytes), total = 335,806,464 (~320.3 MiB):
//   [0        , 110592   ) Wqkv_t bf16 [9][192][32]
//   [110592   , 184320   ) Wo_t   bf16 [9][64][64]
//   [262144   , 67371008 ) q  bf16 [64][1024][512]   (d''-ordered; reused as y_img)
//   [67371008 , 134479872) k  bf16 [64][1024][512]   (pstats overlays after qk)
//   [134479872, 268697600) S   bf16 [64][1024][1024] (raw scaled scores)
//   [268697600, 335806464) vt bf16 [64][512][1024]   (rows = d' = pyix*8+jj)

using bf16 = __hip_bfloat16;
typedef short bf16x8 __attribute__((ext_vector_type(8)));
typedef short bf16x4 __attribute__((ext_vector_type(4)));
typedef float f32x4 __attribute__((ext_vector_type(4)));

#define AS1 __attribute__((address_space(1)))
#define AS3 __attribute__((address_space(3)))

__device__ __forceinline__ void gload_lds16(const void* g, void* l) {
  __builtin_amdgcn_global_load_lds((const AS1 unsigned int*)g, (AS3 unsigned int*)l, 16, 0, 0);
}
__device__ __forceinline__ float b2f(unsigned short u) {
  union { unsigned int i; float f; } x; x.i = ((unsigned)u) << 16; return x.f;
}
__device__ __forceinline__ unsigned short f2b(float f) {
  __hip_bfloat16 h = __float2bfloat16(f);
  return *reinterpret_cast<unsigned short*>(&h);
}

// ---------------- weight prep: f32 OIHW -> bf16 [step][co][ci] ----------------
__global__ __launch_bounds__(256) void prep_w(const float* __restrict__ Wq, const float* __restrict__ Wk,
                                              const float* __restrict__ Wv, const float* __restrict__ Wo,
                                              bf16* __restrict__ wt, bf16* __restrict__ wot) {
  int i = blockIdx.x * 256 + threadIdx.x;
  if (i < 9 * 192 * 32) {              // wt[s][co192][ci]
    int ci = i & 31, co192 = (i >> 5) % 192, s = i / 6144;
    int dy = s / 3, dx = s % 3;
    int proj = co192 >> 6, co = co192 & 63;
    const float* Ws = (proj == 0) ? Wq : ((proj == 1) ? Wk : Wv);
    wt[i] = __float2bfloat16(Ws[((co * 32 + ci) * 3 + dy) * 3 + dx]);
  }
  if (i < 9 * 64 * 64) {               // wot[s][co][ci]
    int ci = i & 63, co = (i >> 6) & 63, s = i >> 12;
    wot[i] = __float2bfloat16(Wo[((co * 64 + ci) * 3 + (s / 3)) * 3 + (s % 3)]);
  }
}

// ---------------- QKV windowed conv: direct d''-ordered stores ----------------
__global__ __launch_bounds__(256) void qkv_conv(const float* __restrict__ x, const bf16* __restrict__ wt,
                                                const float* __restrict__ bq, const float* __restrict__ bk,
                                                const float* __restrict__ bv,
                                                bf16* __restrict__ qout, bf16* __restrict__ kout,
                                                bf16* __restrict__ vout) {
  __shared__ bf16 xp[8000];            // [win][py*10+px][ci pad40], 16 KB
  int tid = threadIdx.x, bid = blockIdx.x;
  int t = bid >> 9, g = bid & 511;
  int gy = g >> 4, gx0 = (g & 15) * 2;

  unsigned int* xp32 = (unsigned int*)xp;
  for (int i = tid; i < 4000; i += 256) xp32[i] = 0u;
  __syncthreads();
  const float* xb = x + (size_t)t * 32 * 65536;
  #pragma unroll
  for (int it = 0; it < 16; ++it) {
    int e = tid + it * 256;
    int ix = e & 7, win = (e >> 3) & 1, iy = (e >> 4) & 7, ci = e >> 7;
    float val = xb[(size_t)ci * 65536 + (gy * 8 + iy) * 256 + (gx0 + win) * 8 + ix];
    xp[(win * 100 + (iy + 1) * 10 + (ix + 1)) * 40 + ci] = __float2bfloat16(val);
  }
  __syncthreads();

  int wv = tid >> 6, l = tid & 63, l15 = l & 15, lg = l >> 4;
  f32x4 z4 = {0.f, 0.f, 0.f, 0.f};
  f32x4 acc[3][8];
  for (int i = 0; i < 3; ++i) for (int j = 0; j < 8; ++j) acc[i][j] = z4;

  #pragma unroll
  for (int s = 0; s < 9; ++s) {
    const int dy = s / 3, dx = s % 3;
    bf16x8 a[3];
    #pragma unroll
    for (int mt = 0; mt < 3; ++mt)
      a[mt] = *(const bf16x8*)&wt[((size_t)s * 192 + wv * 48 + mt * 16 + l15) * 32 + lg * 8];
    #pragma unroll
    for (int nt = 0; nt < 8; ++nt) {
      int n = nt * 16 + l15;
      int win = n >> 6, px = n & 63;
      int iy = px >> 3, ix = px & 7;
      bf16x8 b = *(const bf16x8*)&xp[(win * 100 + (iy + dy) * 10 + (ix + dx)) * 40 + lg * 8];
      #pragma unroll
      for (int mt = 0; mt < 3; ++mt)
        acc[mt][nt] = __builtin_amdgcn_mfma_f32_16x16x32_bf16(a[mt], b, acc[mt][nt], 0, 0, 0);
    }
  }

  #pragma unroll
  for (int mt = 0; mt < 3; ++mt) {
    int c0 = wv * 48 + mt * 16 + lg * 4;
    int proj = c0 >> 6;
    int co0 = c0 & 63;
    int head = co0 >> 3, jj0 = co0 & 7;
    const float* bptr = (proj == 0) ? bq : ((proj == 1) ? bk : bv);
    bf16* dst = (proj == 0) ? qout : ((proj == 1) ? kout : vout);
    float bias[4];
    #pragma unroll
    for (int r = 0; r < 4; ++r) bias[r] = bptr[co0 + r];
    size_t bh = (size_t)(t * 8 + head);
    #pragma unroll
    for (int nt = 0; nt < 8; ++nt) {
      int n = nt * 16 + l15;
      int win2 = n >> 6, pyix = n & 63;
      size_t gwin = (size_t)gy * 32 + gx0 + win2;
      bf16x4 pack;
      #pragma unroll
      for (int r = 0; r < 4; ++r) pack[r] = (short)f2b(acc[mt][nt][r] + bias[r]);
      *(bf16x4*)&dst[(bh * 1024 + gwin) * 512 + pyix * 8 + jj0] = pack;
    }
  }
}

// ---------------- V transpose (plain): [bh][win][d''] -> [bh][d''][win] ----------------
__global__ __launch_bounds__(256) void transpose_v(const bf16* __restrict__ v, bf16* __restrict__ vt) {
  __shared__ bf16 tl[64 * 72];         // [d_local][win pad72]
  int tid = threadIdx.x, bid = blockIdx.x;
  int bh = bid >> 7, wtile = (bid >> 3) & 15, dtile = bid & 7;
  int w0 = wtile * 64, d0 = dtile * 64;
  const bf16* vb = v + ((size_t)bh * 1024 + w0) * 512 + d0;
  int win_l = tid >> 2, dseg = (tid & 3) * 16;
  bf16x8 x0 = *(const bf16x8*)&vb[(size_t)win_l * 512 + dseg];
  bf16x8 x1 = *(const bf16x8*)&vb[(size_t)win_l * 512 + dseg + 8];
  #pragma unroll
  for (int j = 0; j < 8; ++j) {
    *(short*)&tl[(dseg + j) * 72 + win_l] = x0[j];
    *(short*)&tl[(dseg + 8 + j) * 72 + win_l] = x1[j];
  }
  __syncthreads();
  int d_l = tid >> 2, wseg = (tid & 3) * 16;
  bf16x8 y0 = *(const bf16x8*)&tl[d_l * 72 + wseg];
  bf16x8 y1 = *(const bf16x8*)&tl[d_l * 72 + wseg + 8];
  bf16* vtb = vt + ((size_t)bh * 512 + d0 + d_l) * 1024 + w0 + wseg;
  *(bf16x8*)&vtb[0] = y0;
  *(bf16x8*)&vtb[8] = y1;
}

// ---------------- batched QK^T -> S bf16: counted-vmcnt, A-dbuf + B-ring3 ----------------
__global__ __launch_bounds__(512, 1) void qk_gemm(const bf16* __restrict__ q, const bf16* __restrict__ k,
                                                  bf16* __restrict__ S) {
  __shared__ bf16 smem[81920];         // 160 KiB
  int tid = threadIdx.x;
  int bid = (blockIdx.x & 7) * 128 + (blockIdx.x >> 3);    // XCD swizzle (1024 % 8 == 0)
  int batch = bid >> 4, tm = (bid >> 2) & 3, tn = bid & 3;
  const bf16* Qb = q + (size_t)batch * 1024 * 512 + (size_t)tm * 256 * 512;
  const bf16* Kb = k + (size_t)batch * 1024 * 512 + (size_t)tn * 256 * 512;
  int w = tid >> 6, l = tid & 63, l15 = l & 15, lg = l >> 4;
  int wm2 = w >> 2, wn4 = w & 3;
  int lr = l >> 3, sl = (l & 7) ^ lr, swz = l15 & 7;
  f32x4 z4 = {0.f, 0.f, 0.f, 0.f};
  f32x4 acc[8][4];
  for (int i = 0; i < 8; ++i) for (int j = 0; j < 4; ++j) acc[i][j] = z4;

  #define QK_STG_A(T)                                                            \
    { char* base = (char*)smem + ((T) & 1) * 32768;                              \
      _Pragma("unroll")                                                          \
      for (int p = 0; p < 4; ++p) {                                              \
        int row = p * 64 + w * 8 + lr;                                           \
        gload_lds16(Qb + (size_t)row * 512 + (T) * 64 + sl * 8,                  \
                    base + p * 8192 + w * 1024); } }
  #define QK_STG_B(T)                                                            \
    { char* base = (char*)smem + 65536 + ((T) % 3) * 32768;                      \
      _Pragma("unroll")                                                          \
      for (int p = 0; p < 4; ++p) {                                              \
        int row = p * 64 + w * 8 + lr;                                           \
        gload_lds16(Kb + (size_t)row * 512 + (T) * 64 + sl * 8,                  \
                    base + p * 8192 + w * 1024); } }

  QK_STG_B(0); QK_STG_A(0); QK_STG_B(1);
  asm volatile("s_waitcnt vmcnt(4)" ::: "memory");
  __builtin_amdgcn_s_barrier();
  __builtin_amdgcn_sched_barrier(0);

  #pragma unroll
  for (int t = 0; t < 8; ++t) {
    if (t + 1 < 8) QK_STG_A(t + 1);
    if (t + 2 < 8) QK_STG_B(t + 2);
    const bf16* At = (const bf16*)((char*)smem + (t & 1) * 32768);
    const bf16* Bt = (const bf16*)((char*)smem + 65536 + (t % 3) * 32768);
    __builtin_amdgcn_s_setprio(1);
    #pragma unroll
    for (int kk = 0; kk < 2; ++kk) {
      int ps = (kk * 4 + lg) ^ swz;
      bf16x8 a[8], b[4];
      #pragma unroll
      for (int i = 0; i < 8; ++i)
        a[i] = *(const bf16x8*)&At[(wm2 * 128 + i * 16 + l15) * 64 + ps * 8];
      #pragma unroll
      for (int j = 0; j < 4; ++j)
        b[j] = *(const bf16x8*)&Bt[(wn4 * 64 + j * 16 + l15) * 64 + ps * 8];
      #pragma unroll
      for (int i = 0; i < 8; ++i)
        #pragma unroll
        for (int j = 0; j < 4; ++j)
          acc[i][j] = __builtin_amdgcn_mfma_f32_16x16x32_bf16(a[i], b[j], acc[i][j], 0, 0, 0);
    }
    __builtin_amdgcn_s_setprio(0);
    if (t + 2 < 8)      { asm volatile("s_waitcnt vmcnt(4)" ::: "memory"); }
    else if (t + 1 < 8) { asm volatile("s_waitcnt vmcnt(0)" ::: "memory"); }
    __builtin_amdgcn_s_barrier();
    __builtin_amdgcn_sched_barrier(0);
  }
  #undef QK_STG_A
  #undef QK_STG_B

  const float SCALE = 0.04419417382415922f;  // 1/sqrt(512)
  bf16* Sb = S + (size_t)batch * 1024 * 1024;
  #pragma unroll
  for (int i = 0; i < 8; ++i)
    #pragma unroll
    for (int j = 0; j < 4; ++j)
      #pragma unroll
      for (int r = 0; r < 4; ++r) {
        int row = tm * 256 + wm2 * 128 + i * 16 + lg * 4 + r;
        int col = tn * 256 + wn4 * 64 + j * 16 + l15;
        Sb[(size_t)row * 1024 + col] = __float2bfloat16(acc[i][j][r] * SCALE);
      }
}

// ---------------- row stats: per row m = max, rcp = 1/sum(exp(s-m)) ----------------
__global__ __launch_bounds__(256) void row_stats(const bf16* __restrict__ S, float2* __restrict__ pstats) {
  int l = threadIdx.x & 63;
  size_t row = (size_t)blockIdx.x * 4 + (threadIdx.x >> 6);
  const bf16* p = S + row * 1024 + l * 16;
  bf16x8 s0 = *(const bf16x8*)p;
  bf16x8 s1 = *(const bf16x8*)(p + 8);
  float f[16];
  #pragma unroll
  for (int i = 0; i < 8; ++i) { f[i] = b2f((unsigned short)s0[i]); f[8 + i] = b2f((unsigned short)s1[i]); }
  float m = f[0];
  #pragma unroll
  for (int i = 1; i < 16; ++i) m = fmaxf(m, f[i]);
  for (int d = 1; d < 64; d <<= 1) m = fmaxf(m, __shfl_xor(m, d));
  float sum = 0.f;
  #pragma unroll
  for (int i = 0; i < 16; ++i) sum += __expf(f[i] - m);
  for (int d = 1; d < 64; d <<= 1) sum += __shfl_xor(sum, d);
  if (l == 0) {
    float2 st; st.x = m; st.y = 1.0f / sum;
    pstats[row] = st;
  }
}

// ---------------- batched PV: counted-vmcnt, A(exp)-dbuf + B-ring3, sandwiched transform ----------------
// Phase t: issue A(t+1) regs + B(t+2); kk=0 MFMAs; vmcnt(4) [drains B(t+1)+A(t+1)];
// transform+write A(t+1); kk=1 MFMAs; lgkm(0); barrier. No tail vmcnt.
__global__ __launch_bounds__(512, 1) void pv_gemm(const bf16* __restrict__ S, const bf16* __restrict__ vt,
                                                  const float2* __restrict__ pstats,
                                                  bf16* __restrict__ y) {
  __shared__ bf16 smem[81920];         // 160 KiB: A buf c at c*32768 B; B slot s at 65536+s*32768 B
  int tid = threadIdx.x;
  int bid = (blockIdx.x & 7) * 64 + (blockIdx.x >> 3);     // XCD swizzle (512 % 8 == 0)
  int batch = bid >> 3, bq = (bid >> 1) & 3, bd = bid & 1;
  const bf16* Pb = S + (size_t)batch * 1024 * 1024 + (size_t)bq * 256 * 1024;
  const bf16* Vb = vt + (size_t)batch * 512 * 1024 + (size_t)bd * 256 * 1024;
  int w = tid >> 6, l = tid & 63, l15 = l & 15, lg = l >> 4;
  int wm2 = w >> 2, wn4 = w & 3;
  int lr = l >> 3, sl = (l & 7) ^ lr, swz = l15 & 7;
  f32x4 z4 = {0.f, 0.f, 0.f, 0.f};
  f32x4 acc[8][4];
  for (int i = 0; i < 8; ++i) for (int j = 0; j < 4; ++j) acc[i][j] = z4;

  float m4[4], r4[4];
  #pragma unroll
  for (int p = 0; p < 4; ++p) {
    float2 st = pstats[(size_t)batch * 1024 + bq * 256 + p * 64 + w * 8 + lr];
    m4[p] = st.x; r4[p] = st.y;
  }

  bf16x8 areg[4];
  #define PV_ISSUE_A(tt)                                                          \
    { _Pragma("unroll")                                                           \
      for (int p = 0; p < 4; ++p)                                                 \
        areg[p] = *(const bf16x8*)&Pb[(size_t)(p * 64 + w * 8 + lr) * 1024 +      \
                                      (tt) * 64 + sl * 8]; }
  #define PV_STG_B(T)                                                             \
    { char* base = (char*)smem + 65536 + ((T) % 3) * 32768;                       \
      _Pragma("unroll")                                                           \
      for (int p = 0; p < 4; ++p) {                                               \
        int row = p * 64 + w * 8 + lr;                                            \
        gload_lds16(Vb + (size_t)row * 1024 + (T) * 64 + sl * 8,                  \
                    base + p * 8192 + w * 1024); } }
  #define PV_WRITE_A(buf)                                                         \
    { char* base = (char*)smem + (buf) * 32768;                                   \
      _Pragma("unroll")                                                           \
      for (int p = 0; p < 4; ++p) {                                               \
        bf16x8 o;                                                                 \
        _Pragma("unroll")                                                         \
        for (int e = 0; e < 8; ++e) {                                             \
          float fv = b2f((unsigned short)areg[p][e]);                             \
          o[e] = (short)f2b(__expf(fv - m4[p]) * r4[p]);                          \
        }                                                                         \
        *(bf16x8*)(base + p * 8192 + w * 1024 + l * 16) = o; }                    \
    }

  // prologue: B0, A0(regs), B1 (oldest first); vmcnt(4) drains B0+A0; transform A0.
  PV_STG_B(0); PV_ISSUE_A(0); PV_STG_B(1);
  asm volatile("s_waitcnt vmcnt(4)" ::: "memory");
  PV_WRITE_A(0);
  asm volatile("s_waitcnt lgkmcnt(0)" ::: "memory");
  __builtin_amdgcn_s_barrier();
  __builtin_amdgcn_sched_barrier(0);

  #pragma unroll
  for (int t = 0; t < 16; ++t) {
    if (t + 1 < 16) PV_ISSUE_A(t + 1);
    if (t + 2 < 16) PV_STG_B(t + 2);
    const bf16* At = (const bf16*)((char*)smem + (t & 1) * 32768);
    const bf16* Bt = (const bf16*)((char*)smem + 65536 + (t % 3) * 32768);

    // kk = 0 half
    {
      int ps = lg ^ swz;
      bf16x8 a[8], b[4];
      #pragma unroll
      for (int i = 0; i < 8; ++i)
        a[i] = *(const bf16x8*)&At[(wm2 * 128 + i * 16 + l15) * 64 + ps * 8];
      #pragma unroll
      for (int j = 0; j < 4; ++j)
        b[j] = *(const bf16x8*)&Bt[(wn4 * 64 + j * 16 + l15) * 64 + ps * 8];
      asm volatile("s_waitcnt lgkmcnt(0)" ::: "memory");
      __builtin_amdgcn_sched_barrier(0);
      __builtin_amdgcn_s_setprio(1);
      #pragma unroll
      for (int i = 0; i < 8; ++i)
        #pragma unroll
        for (int j = 0; j < 4; ++j)
          acc[i][j] = __builtin_amdgcn_mfma_f32_16x16x32_bf16(a[i], b[j], acc[i][j], 0, 0, 0);
      __builtin_amdgcn_s_setprio(0);
    }

    // sandwiched A(t+1) transform: regs arrived (vmcnt drains B(t+1)+A(t+1))
    if (t + 1 < 16) {
      if (t + 2 < 16) { asm volatile("s_waitcnt vmcnt(4)" ::: "memory"); }
      else            { asm volatile("s_waitcnt vmcnt(0)" ::: "memory"); }
      PV_WRITE_A((t + 1) & 1);
    }

    // kk = 1 half
    {
      int ps = (4 + lg) ^ swz;
      bf16x8 a[8], b[4];
      #pragma unroll
      for (int i = 0; i < 8; ++i)
        a[i] = *(const bf16x8*)&At[(wm2 * 128 + i * 16 + l15) * 64 + ps * 8];
      #pragma unroll
      for (int j = 0; j < 4; ++j)
        b[j] = *(const bf16x8*)&Bt[(wn4 * 64 + j * 16 + l15) * 64 + ps * 8];
      __builtin_amdgcn_s_setprio(1);
      #pragma unroll
      for (int i = 0; i < 8; ++i)
        #pragma unroll
        for (int j = 0; j < 4; ++j)
          acc[i][j] = __builtin_amdgcn_mfma_f32_16x16x32_bf16(a[i], b[j], acc[i][j], 0, 0, 0);
      __builtin_amdgcn_s_setprio(0);
    }

    asm volatile("s_waitcnt lgkmcnt(0)" ::: "memory");
    __builtin_amdgcn_s_barrier();
    __builtin_amdgcn_sched_barrier(0);
  }
  #undef PV_ISSUE_A
  #undef PV_STG_B
  #undef PV_WRITE_A

  // epilogue: direct channels-last stores (16B runs per 8 lanes)
  int t2 = batch >> 3, h = batch & 7;
  #pragma unroll
  for (int i = 0; i < 8; ++i)
    #pragma unroll
    for (int j = 0; j < 4; ++j)
      #pragma unroll
      for (int r = 0; r < 4; ++r) {
        int win = bq * 256 + wm2 * 128 + i * 16 + lg * 4 + r;
        int dp = bd * 256 + wn4 * 64 + j * 16 + l15;
        int jj = dp & 7, pyix = dp >> 3;
        int gy = win >> 5, gx = win & 31;
        int Y = gy * 8 + (pyix >> 3), X = gx * 8 + (pyix & 7);
        y[(((size_t)t2 * 256 + Y) * 256 + X) * 64 + h * 8 + jj] = __float2bfloat16(acc[i][j][r]);
      }
}

// ---------------- final full-image conv + residual -> f32 out (8 waves) ----------------
__global__ __launch_bounds__(512) void out_conv(const bf16* __restrict__ yimg, const bf16* __restrict__ wot,
                                                const float* __restrict__ bo, float* __restrict__ out) {
  __shared__ bf16 yp[324 * 76];        // [py*18+px][ci pad76]
  int tid = threadIdx.x, bid = blockIdx.x;
  int t = bid >> 8, tile = bid & 255;
  int y0 = (tile >> 4) * 16, x0 = (tile & 15) * 16;
  const bf16* yb = yimg + (size_t)t * 256 * 256 * 64;

  for (int e = tid; e < 324 * 8; e += 512) {
    int seg = e & 7, pos = e >> 3;
    int ppx = pos % 18, ppy = pos / 18;
    int gy = y0 + ppy - 1, gx = x0 + ppx - 1;
    bf16x8 val = {0, 0, 0, 0, 0, 0, 0, 0};
    if ((unsigned)gy < 256u && (unsigned)gx < 256u)
      val = *(const bf16x8*)&yb[((size_t)gy * 256 + gx) * 64 + seg * 8];
    *(bf16x8*)&yp[pos * 76 + seg * 8] = val;
  }
  __syncthreads();

  int w = tid >> 6, l = tid & 63, l15 = l & 15, lg = l >> 4;
  int wm = w & 1, wn = w >> 1;         // wn 0..3: 4 ty rows each
  f32x4 z4 = {0.f, 0.f, 0.f, 0.f};
  f32x4 acc[2][4];
  for (int i = 0; i < 2; ++i) for (int j = 0; j < 4; ++j) acc[i][j] = z4;

  #pragma unroll
  for (int s9 = 0; s9 < 9; ++s9) {
    const int dy = s9 / 3, dx = s9 % 3;
    #pragma unroll
    for (int half = 0; half < 2; ++half) {
      bf16x8 a[2];
      #pragma unroll
      for (int mt = 0; mt < 2; ++mt)
        a[mt] = *(const bf16x8*)&wot[((size_t)s9 * 64 + wm * 32 + mt * 16 + l15) * 64 + half * 32 + lg * 8];
      #pragma unroll
      for (int nt = 0; nt < 4; ++nt) {
        int ty = wn * 4 + nt;
        bf16x8 b = *(const bf16x8*)&yp[((ty + dy) * 18 + l15 + dx) * 76 + half * 32 + lg * 8];
        #pragma unroll
        for (int mt = 0; mt < 2; ++mt)
          acc[mt][nt] = __builtin_amdgcn_mfma_f32_16x16x32_bf16(a[mt], b, acc[mt][nt], 0, 0, 0);
      }
    }
  }

  float* ob = out + (size_t)t * 64 * 65536;
  float bias[2][4];
  #pragma unroll
  for (int mt = 0; mt < 2; ++mt)
    #pragma unroll
    for (int r = 0; r < 4; ++r) bias[mt][r] = bo[wm * 32 + mt * 16 + lg * 4 + r];
  #pragma unroll
  for (int mt = 0; mt < 2; ++mt)
    #pragma unroll
    for (int nt = 0; nt < 4; ++nt) {
      int ty = wn * 4 + nt;
      bf16x4 resv = *(const bf16x4*)&yp[((ty + 1) * 18 + l15 + 1) * 76 + wm * 32 + mt * 16 + lg * 4];
      #pragma unroll
      for (int r = 0; r < 4; ++r) {
        int co = wm * 32 + mt * 16 + lg * 4 + r;
        float res = b2f((unsigned short)resv[r]);
        ob[(size_t)co * 65536 + (size_t)(y0 + ty) * 256 + x0 + l15] = res + acc[mt][nt][r] + bias[mt][r];
      }
    }
}

// ---------------- launcher ----------------
extern "C" void kernel_launch(void* const* d_in, const int* in_sizes, int n_in,
                              void* d_out, int out_size, void* d_ws, size_t ws_size,
                              hipStream_t stream) {
  const float* x  = (const float*)d_in[0];
  const float* Wq = (const float*)d_in[1];
  const float* bq = (const float*)d_in[2];
  const float* Wk = (const float*)d_in[3];
  const float* bk = (const float*)d_in[4];
  const float* Wv = (const float*)d_in[5];
  const float* bv = (const float*)d_in[6];
  const float* Wo = (const float*)d_in[7];
  const float* bo = (const float*)d_in[8];
  float* out = (float*)d_out;

  char* ws = (char*)d_ws;
  bf16* wt  = (bf16*)(ws + 0);
  bf16* wot = (bf16*)(ws + 110592);
  bf16* q   = (bf16*)(ws + 262144);              // reused as y_img after qk_gemm
  bf16* k   = (bf16*)(ws + 67371008);
  float2* pstats = (float2*)(ws + 67371008);     // overlaps k (dead after qk_gemm)
  bf16* S   = (bf16*)(ws + 134479872);
  bf16* vt  = (bf16*)(ws + 268697600);
  bf16* y   = (bf16*)(ws + 262144);              // channels-last [8][256][256][64]
  bf16* v   = S;                                 // v staged where S will go (dead before qk)
  // requires ws_size >= 335,806,464 bytes

  prep_w<<<216, 256, 0, stream>>>(Wq, Wk, Wv, Wo, wt, wot);
  qkv_conv<<<4096, 256, 0, stream>>>(x, wt, bq, bk, bv, q, k, v);
  transpose_v<<<8192, 256, 0, stream>>>(v, vt);
  qk_gemm<<<1024, 512, 0, stream>>>(q, k, S);
  row_stats<<<16384, 256, 0, stream>>>(S, pstats);
  pv_gemm<<<512, 512, 0, stream>>>(S, vt, pstats, y);
  out_conv<<<2048, 512, 0, stream>>>(y, wot, bo, out);
}

// Round 16
// 434.638 us; speedup vs baseline: 1.0221x; 1.0221x over previous
//
#include <hip/hip_runtime.h>
#include <hip/hip_bf16.h>
#include <stdint.h>

// Spatial local attention, MI355X bf16-MFMA implementation.
// Round 16: best-of assembly. pv_gemm reverted to round-14 (A-dbuf + B-ring3,
// tail transform). qk ring, qkv d''-direct, transpose_v, row_stats unchanged.
// out_conv stays 8-wave (round-15).
//
// Workspace layout (bytes), total = 335,806,464 (~320.3 MiB):
//   [0        , 110592   ) Wqkv_t bf16 [9][192][32]
//   [110592   , 184320   ) Wo_t   bf16 [9][64][64]
//   [262144   , 67371008 ) q  bf16 [64][1024][512]   (d''-ordered; reused as y_img)
//   [67371008 , 134479872) k  bf16 [64][1024][512]   (pstats overlays after qk)
//   [134479872, 268697600) S   bf16 [64][1024][1024] (raw scaled scores)
//   [268697600, 335806464) vt bf16 [64][512][1024]   (rows = d' = pyix*8+jj)

using bf16 = __hip_bfloat16;
typedef short bf16x8 __attribute__((ext_vector_type(8)));
typedef short bf16x4 __attribute__((ext_vector_type(4)));
typedef float f32x4 __attribute__((ext_vector_type(4)));

#define AS1 __attribute__((address_space(1)))
#define AS3 __attribute__((address_space(3)))

__device__ __forceinline__ void gload_lds16(const void* g, void* l) {
  __builtin_amdgcn_global_load_lds((const AS1 unsigned int*)g, (AS3 unsigned int*)l, 16, 0, 0);
}
__device__ __forceinline__ float b2f(unsigned short u) {
  union { unsigned int i; float f; } x; x.i = ((unsigned)u) << 16; return x.f;
}
__device__ __forceinline__ unsigned short f2b(float f) {
  __hip_bfloat16 h = __float2bfloat16(f);
  return *reinterpret_cast<unsigned short*>(&h);
}

// ---------------- weight prep: f32 OIHW -> bf16 [step][co][ci] ----------------
__global__ __launch_bounds__(256) void prep_w(const float* __restrict__ Wq, const float* __restrict__ Wk,
                                              const float* __restrict__ Wv, const float* __restrict__ Wo,
                                              bf16* __restrict__ wt, bf16* __restrict__ wot) {
  int i = blockIdx.x * 256 + threadIdx.x;
  if (i < 9 * 192 * 32) {              // wt[s][co192][ci]
    int ci = i & 31, co192 = (i >> 5) % 192, s = i / 6144;
    int dy = s / 3, dx = s % 3;
    int proj = co192 >> 6, co = co192 & 63;
    const float* Ws = (proj == 0) ? Wq : ((proj == 1) ? Wk : Wv);
    wt[i] = __float2bfloat16(Ws[((co * 32 + ci) * 3 + dy) * 3 + dx]);
  }
  if (i < 9 * 64 * 64) {               // wot[s][co][ci]
    int ci = i & 63, co = (i >> 6) & 63, s = i >> 12;
    wot[i] = __float2bfloat16(Wo[((co * 64 + ci) * 3 + (s / 3)) * 3 + (s % 3)]);
  }
}

// ---------------- QKV windowed conv: direct d''-ordered stores ----------------
__global__ __launch_bounds__(256) void qkv_conv(const float* __restrict__ x, const bf16* __restrict__ wt,
                                                const float* __restrict__ bq, const float* __restrict__ bk,
                                                const float* __restrict__ bv,
                                                bf16* __restrict__ qout, bf16* __restrict__ kout,
                                                bf16* __restrict__ vout) {
  __shared__ bf16 xp[8000];            // [win][py*10+px][ci pad40], 16 KB
  int tid = threadIdx.x, bid = blockIdx.x;
  int t = bid >> 9, g = bid & 511;
  int gy = g >> 4, gx0 = (g & 15) * 2;

  unsigned int* xp32 = (unsigned int*)xp;
  for (int i = tid; i < 4000; i += 256) xp32[i] = 0u;
  __syncthreads();
  const float* xb = x + (size_t)t * 32 * 65536;
  #pragma unroll
  for (int it = 0; it < 16; ++it) {
    int e = tid + it * 256;
    int ix = e & 7, win = (e >> 3) & 1, iy = (e >> 4) & 7, ci = e >> 7;
    float val = xb[(size_t)ci * 65536 + (gy * 8 + iy) * 256 + (gx0 + win) * 8 + ix];
    xp[(win * 100 + (iy + 1) * 10 + (ix + 1)) * 40 + ci] = __float2bfloat16(val);
  }
  __syncthreads();

  int wv = tid >> 6, l = tid & 63, l15 = l & 15, lg = l >> 4;
  f32x4 z4 = {0.f, 0.f, 0.f, 0.f};
  f32x4 acc[3][8];
  for (int i = 0; i < 3; ++i) for (int j = 0; j < 8; ++j) acc[i][j] = z4;

  #pragma unroll
  for (int s = 0; s < 9; ++s) {
    const int dy = s / 3, dx = s % 3;
    bf16x8 a[3];
    #pragma unroll
    for (int mt = 0; mt < 3; ++mt)
      a[mt] = *(const bf16x8*)&wt[((size_t)s * 192 + wv * 48 + mt * 16 + l15) * 32 + lg * 8];
    #pragma unroll
    for (int nt = 0; nt < 8; ++nt) {
      int n = nt * 16 + l15;
      int win = n >> 6, px = n & 63;
      int iy = px >> 3, ix = px & 7;
      bf16x8 b = *(const bf16x8*)&xp[(win * 100 + (iy + dy) * 10 + (ix + dx)) * 40 + lg * 8];
      #pragma unroll
      for (int mt = 0; mt < 3; ++mt)
        acc[mt][nt] = __builtin_amdgcn_mfma_f32_16x16x32_bf16(a[mt], b, acc[mt][nt], 0, 0, 0);
    }
  }

  #pragma unroll
  for (int mt = 0; mt < 3; ++mt) {
    int c0 = wv * 48 + mt * 16 + lg * 4;
    int proj = c0 >> 6;
    int co0 = c0 & 63;
    int head = co0 >> 3, jj0 = co0 & 7;
    const float* bptr = (proj == 0) ? bq : ((proj == 1) ? bk : bv);
    bf16* dst = (proj == 0) ? qout : ((proj == 1) ? kout : vout);
    float bias[4];
    #pragma unroll
    for (int r = 0; r < 4; ++r) bias[r] = bptr[co0 + r];
    size_t bh = (size_t)(t * 8 + head);
    #pragma unroll
    for (int nt = 0; nt < 8; ++nt) {
      int n = nt * 16 + l15;
      int win2 = n >> 6, pyix = n & 63;
      size_t gwin = (size_t)gy * 32 + gx0 + win2;
      bf16x4 pack;
      #pragma unroll
      for (int r = 0; r < 4; ++r) pack[r] = (short)f2b(acc[mt][nt][r] + bias[r]);
      *(bf16x4*)&dst[(bh * 1024 + gwin) * 512 + pyix * 8 + jj0] = pack;
    }
  }
}

// ---------------- V transpose (plain): [bh][win][d''] -> [bh][d''][win] ----------------
__global__ __launch_bounds__(256) void transpose_v(const bf16* __restrict__ v, bf16* __restrict__ vt) {
  __shared__ bf16 tl[64 * 72];         // [d_local][win pad72]
  int tid = threadIdx.x, bid = blockIdx.x;
  int bh = bid >> 7, wtile = (bid >> 3) & 15, dtile = bid & 7;
  int w0 = wtile * 64, d0 = dtile * 64;
  const bf16* vb = v + ((size_t)bh * 1024 + w0) * 512 + d0;
  int win_l = tid >> 2, dseg = (tid & 3) * 16;
  bf16x8 x0 = *(const bf16x8*)&vb[(size_t)win_l * 512 + dseg];
  bf16x8 x1 = *(const bf16x8*)&vb[(size_t)win_l * 512 + dseg + 8];
  #pragma unroll
  for (int j = 0; j < 8; ++j) {
    *(short*)&tl[(dseg + j) * 72 + win_l] = x0[j];
    *(short*)&tl[(dseg + 8 + j) * 72 + win_l] = x1[j];
  }
  __syncthreads();
  int d_l = tid >> 2, wseg = (tid & 3) * 16;
  bf16x8 y0 = *(const bf16x8*)&tl[d_l * 72 + wseg];
  bf16x8 y1 = *(const bf16x8*)&tl[d_l * 72 + wseg + 8];
  bf16* vtb = vt + ((size_t)bh * 512 + d0 + d_l) * 1024 + w0 + wseg;
  *(bf16x8*)&vtb[0] = y0;
  *(bf16x8*)&vtb[8] = y1;
}

// ---------------- batched QK^T -> S bf16: counted-vmcnt, A-dbuf + B-ring3 ----------------
__global__ __launch_bounds__(512, 1) void qk_gemm(const bf16* __restrict__ q, const bf16* __restrict__ k,
                                                  bf16* __restrict__ S) {
  __shared__ bf16 smem[81920];         // 160 KiB
  int tid = threadIdx.x;
  int bid = (blockIdx.x & 7) * 128 + (blockIdx.x >> 3);    // XCD swizzle (1024 % 8 == 0)
  int batch = bid >> 4, tm = (bid >> 2) & 3, tn = bid & 3;
  const bf16* Qb = q + (size_t)batch * 1024 * 512 + (size_t)tm * 256 * 512;
  const bf16* Kb = k + (size_t)batch * 1024 * 512 + (size_t)tn * 256 * 512;
  int w = tid >> 6, l = tid & 63, l15 = l & 15, lg = l >> 4;
  int wm2 = w >> 2, wn4 = w & 3;
  int lr = l >> 3, sl = (l & 7) ^ lr, swz = l15 & 7;
  f32x4 z4 = {0.f, 0.f, 0.f, 0.f};
  f32x4 acc[8][4];
  for (int i = 0; i < 8; ++i) for (int j = 0; j < 4; ++j) acc[i][j] = z4;

  #define QK_STG_A(T)                                                            \
    { char* base = (char*)smem + ((T) & 1) * 32768;                              \
      _Pragma("unroll")                                                          \
      for (int p = 0; p < 4; ++p) {                                              \
        int row = p * 64 + w * 8 + lr;                                           \
        gload_lds16(Qb + (size_t)row * 512 + (T) * 64 + sl * 8,                  \
                    base + p * 8192 + w * 1024); } }
  #define QK_STG_B(T)                                                            \
    { char* base = (char*)smem + 65536 + ((T) % 3) * 32768;                      \
      _Pragma("unroll")                                                          \
      for (int p = 0; p < 4; ++p) {                                              \
        int row = p * 64 + w * 8 + lr;                                           \
        gload_lds16(Kb + (size_t)row * 512 + (T) * 64 + sl * 8,                  \
                    base + p * 8192 + w * 1024); } }

  QK_STG_B(0); QK_STG_A(0); QK_STG_B(1);
  asm volatile("s_waitcnt vmcnt(4)" ::: "memory");
  __builtin_amdgcn_s_barrier();
  __builtin_amdgcn_sched_barrier(0);

  #pragma unroll
  for (int t = 0; t < 8; ++t) {
    if (t + 1 < 8) QK_STG_A(t + 1);
    if (t + 2 < 8) QK_STG_B(t + 2);
    const bf16* At = (const bf16*)((char*)smem + (t & 1) * 32768);
    const bf16* Bt = (const bf16*)((char*)smem + 65536 + (t % 3) * 32768);
    __builtin_amdgcn_s_setprio(1);
    #pragma unroll
    for (int kk = 0; kk < 2; ++kk) {
      int ps = (kk * 4 + lg) ^ swz;
      bf16x8 a[8], b[4];
      #pragma unroll
      for (int i = 0; i < 8; ++i)
        a[i] = *(const bf16x8*)&At[(wm2 * 128 + i * 16 + l15) * 64 + ps * 8];
      #pragma unroll
      for (int j = 0; j < 4; ++j)
        b[j] = *(const bf16x8*)&Bt[(wn4 * 64 + j * 16 + l15) * 64 + ps * 8];
      #pragma unroll
      for (int i = 0; i < 8; ++i)
        #pragma unroll
        for (int j = 0; j < 4; ++j)
          acc[i][j] = __builtin_amdgcn_mfma_f32_16x16x32_bf16(a[i], b[j], acc[i][j], 0, 0, 0);
    }
    __builtin_amdgcn_s_setprio(0);
    if (t + 2 < 8)      { asm volatile("s_waitcnt vmcnt(4)" ::: "memory"); }
    else if (t + 1 < 8) { asm volatile("s_waitcnt vmcnt(0)" ::: "memory"); }
    __builtin_amdgcn_s_barrier();
    __builtin_amdgcn_sched_barrier(0);
  }
  #undef QK_STG_A
  #undef QK_STG_B

  const float SCALE = 0.04419417382415922f;  // 1/sqrt(512)
  bf16* Sb = S + (size_t)batch * 1024 * 1024;
  #pragma unroll
  for (int i = 0; i < 8; ++i)
    #pragma unroll
    for (int j = 0; j < 4; ++j)
      #pragma unroll
      for (int r = 0; r < 4; ++r) {
        int row = tm * 256 + wm2 * 128 + i * 16 + lg * 4 + r;
        int col = tn * 256 + wn4 * 64 + j * 16 + l15;
        Sb[(size_t)row * 1024 + col] = __float2bfloat16(acc[i][j][r] * SCALE);
      }
}

// ---------------- row stats: per row m = max, rcp = 1/sum(exp(s-m)) ----------------
__global__ __launch_bounds__(256) void row_stats(const bf16* __restrict__ S, float2* __restrict__ pstats) {
  int l = threadIdx.x & 63;
  size_t row = (size_t)blockIdx.x * 4 + (threadIdx.x >> 6);
  const bf16* p = S + row * 1024 + l * 16;
  bf16x8 s0 = *(const bf16x8*)p;
  bf16x8 s1 = *(const bf16x8*)(p + 8);
  float f[16];
  #pragma unroll
  for (int i = 0; i < 8; ++i) { f[i] = b2f((unsigned short)s0[i]); f[8 + i] = b2f((unsigned short)s1[i]); }
  float m = f[0];
  #pragma unroll
  for (int i = 1; i < 16; ++i) m = fmaxf(m, f[i]);
  for (int d = 1; d < 64; d <<= 1) m = fmaxf(m, __shfl_xor(m, d));
  float sum = 0.f;
  #pragma unroll
  for (int i = 0; i < 16; ++i) sum += __expf(f[i] - m);
  for (int d = 1; d < 64; d <<= 1) sum += __shfl_xor(sum, d);
  if (l == 0) {
    float2 st; st.x = m; st.y = 1.0f / sum;
    pstats[row] = st;
  }
}

// ---------------- batched PV: counted-vmcnt, A(exp)-dbuf + B-ring3 (round-14) ----------------
__global__ __launch_bounds__(512, 1) void pv_gemm(const bf16* __restrict__ S, const bf16* __restrict__ vt,
                                                  const float2* __restrict__ pstats,
                                                  bf16* __restrict__ y) {
  __shared__ bf16 smem[81920];         // 160 KiB: A buf c at c*32768 B; B slot s at 65536+s*32768 B
  int tid = threadIdx.x;
  int bid = (blockIdx.x & 7) * 64 + (blockIdx.x >> 3);     // XCD swizzle (512 % 8 == 0)
  int batch = bid >> 3, bq = (bid >> 1) & 3, bd = bid & 1;
  const bf16* Pb = S + (size_t)batch * 1024 * 1024 + (size_t)bq * 256 * 1024;
  const bf16* Vb = vt + (size_t)batch * 512 * 1024 + (size_t)bd * 256 * 1024;
  int w = tid >> 6, l = tid & 63, l15 = l & 15, lg = l >> 4;
  int wm2 = w >> 2, wn4 = w & 3;
  int lr = l >> 3, sl = (l & 7) ^ lr, swz = l15 & 7;
  f32x4 z4 = {0.f, 0.f, 0.f, 0.f};
  f32x4 acc[8][4];
  for (int i = 0; i < 8; ++i) for (int j = 0; j < 4; ++j) acc[i][j] = z4;

  float m4[4], r4[4];
  #pragma unroll
  for (int p = 0; p < 4; ++p) {
    float2 st = pstats[(size_t)batch * 1024 + bq * 256 + p * 64 + w * 8 + lr];
    m4[p] = st.x; r4[p] = st.y;
  }

  bf16x8 areg[4];
  #define PV_ISSUE_A(tt)                                                          \
    { _Pragma("unroll")                                                           \
      for (int p = 0; p < 4; ++p)                                                 \
        areg[p] = *(const bf16x8*)&Pb[(size_t)(p * 64 + w * 8 + lr) * 1024 +      \
                                      (tt) * 64 + sl * 8]; }
  #define PV_STG_B(T)                                                             \
    { char* base = (char*)smem + 65536 + ((T) % 3) * 32768;                       \
      _Pragma("unroll")                                                           \
      for (int p = 0; p < 4; ++p) {                                               \
        int row = p * 64 + w * 8 + lr;                                            \
        gload_lds16(Vb + (size_t)row * 1024 + (T) * 64 + sl * 8,                  \
                    base + p * 8192 + w * 1024); } }
  #define PV_WRITE_A(buf)                                                         \
    { char* base = (char*)smem + (buf) * 32768;                                   \
      _Pragma("unroll")                                                           \
      for (int p = 0; p < 4; ++p) {                                               \
        bf16x8 o;                                                                 \
        _Pragma("unroll")                                                         \
        for (int e = 0; e < 8; ++e) {                                             \
          float fv = b2f((unsigned short)areg[p][e]);                             \
          o[e] = (short)f2b(__expf(fv - m4[p]) * r4[p]);                          \
        }                                                                         \
        *(bf16x8*)(base + p * 8192 + w * 1024 + l * 16) = o; }                    \
    }

  // prologue: B0, A0(regs), B1 (oldest first); vmcnt(4) drains B0+A0; transform A0.
  PV_STG_B(0); PV_ISSUE_A(0); PV_STG_B(1);
  asm volatile("s_waitcnt vmcnt(4)" ::: "memory");
  PV_WRITE_A(0);
  asm volatile("s_waitcnt lgkmcnt(0)" ::: "memory");
  __builtin_amdgcn_s_barrier();
  __builtin_amdgcn_sched_barrier(0);

  #pragma unroll
  for (int t = 0; t < 16; ++t) {
    if (t + 1 < 16) PV_ISSUE_A(t + 1);
    if (t + 2 < 16) PV_STG_B(t + 2);
    const bf16* At = (const bf16*)((char*)smem + (t & 1) * 32768);
    const bf16* Bt = (const bf16*)((char*)smem + 65536 + (t % 3) * 32768);
    __builtin_amdgcn_s_setprio(1);
    #pragma unroll
    for (int kk = 0; kk < 2; ++kk) {
      int ps = (kk * 4 + lg) ^ swz;
      bf16x8 a[8], b[4];
      #pragma unroll
      for (int i = 0; i < 8; ++i)
        a[i] = *(const bf16x8*)&At[(wm2 * 128 + i * 16 + l15) * 64 + ps * 8];
      #pragma unroll
      for (int j = 0; j < 4; ++j)
        b[j] = *(const bf16x8*)&Bt[(wn4 * 64 + j * 16 + l15) * 64 + ps * 8];
      #pragma unroll
      for (int i = 0; i < 8; ++i)
        #pragma unroll
        for (int j = 0; j < 4; ++j)
          acc[i][j] = __builtin_amdgcn_mfma_f32_16x16x32_bf16(a[i], b[j], acc[i][j], 0, 0, 0);
    }
    __builtin_amdgcn_s_setprio(0);
    if (t + 2 < 16)      { asm volatile("s_waitcnt vmcnt(4)" ::: "memory"); }
    else if (t + 1 < 16) { asm volatile("s_waitcnt vmcnt(0)" ::: "memory"); }
    if (t + 1 < 16) PV_WRITE_A((t + 1) & 1);
    asm volatile("s_waitcnt lgkmcnt(0)" ::: "memory");
    __builtin_amdgcn_s_barrier();
    __builtin_amdgcn_sched_barrier(0);
  }
  #undef PV_ISSUE_A
  #undef PV_STG_B
  #undef PV_WRITE_A

  // epilogue: direct channels-last stores (16B runs per 8 lanes)
  int t2 = batch >> 3, h = batch & 7;
  #pragma unroll
  for (int i = 0; i < 8; ++i)
    #pragma unroll
    for (int j = 0; j < 4; ++j)
      #pragma unroll
      for (int r = 0; r < 4; ++r) {
        int win = bq * 256 + wm2 * 128 + i * 16 + lg * 4 + r;
        int dp = bd * 256 + wn4 * 64 + j * 16 + l15;
        int jj = dp & 7, pyix = dp >> 3;
        int gy = win >> 5, gx = win & 31;
        int Y = gy * 8 + (pyix >> 3), X = gx * 8 + (pyix & 7);
        y[(((size_t)t2 * 256 + Y) * 256 + X) * 64 + h * 8 + jj] = __float2bfloat16(acc[i][j][r]);
      }
}

// ---------------- final full-image conv + residual -> f32 out (8 waves) ----------------
__global__ __launch_bounds__(512) void out_conv(const bf16* __restrict__ yimg, const bf16* __restrict__ wot,
                                                const float* __restrict__ bo, float* __restrict__ out) {
  __shared__ bf16 yp[324 * 76];        // [py*18+px][ci pad76]
  int tid = threadIdx.x, bid = blockIdx.x;
  int t = bid >> 8, tile = bid & 255;
  int y0 = (tile >> 4) * 16, x0 = (tile & 15) * 16;
  const bf16* yb = yimg + (size_t)t * 256 * 256 * 64;

  for (int e = tid; e < 324 * 8; e += 512) {
    int seg = e & 7, pos = e >> 3;
    int ppx = pos % 18, ppy = pos / 18;
    int gy = y0 + ppy - 1, gx = x0 + ppx - 1;
    bf16x8 val = {0, 0, 0, 0, 0, 0, 0, 0};
    if ((unsigned)gy < 256u && (unsigned)gx < 256u)
      val = *(const bf16x8*)&yb[((size_t)gy * 256 + gx) * 64 + seg * 8];
    *(bf16x8*)&yp[pos * 76 + seg * 8] = val;
  }
  __syncthreads();

  int w = tid >> 6, l = tid & 63, l15 = l & 15, lg = l >> 4;
  int wm = w & 1, wn = w >> 1;         // wn 0..3: 4 ty rows each
  f32x4 z4 = {0.f, 0.f, 0.f, 0.f};
  f32x4 acc[2][4];
  for (int i = 0; i < 2; ++i) for (int j = 0; j < 4; ++j) acc[i][j] = z4;

  #pragma unroll
  for (int s9 = 0; s9 < 9; ++s9) {
    const int dy = s9 / 3, dx = s9 % 3;
    #pragma unroll
    for (int half = 0; half < 2; ++half) {
      bf16x8 a[2];
      #pragma unroll
      for (int mt = 0; mt < 2; ++mt)
        a[mt] = *(const bf16x8*)&wot[((size_t)s9 * 64 + wm * 32 + mt * 16 + l15) * 64 + half * 32 + lg * 8];
      #pragma unroll
      for (int nt = 0; nt < 4; ++nt) {
        int ty = wn * 4 + nt;
        bf16x8 b = *(const bf16x8*)&yp[((ty + dy) * 18 + l15 + dx) * 76 + half * 32 + lg * 8];
        #pragma unroll
        for (int mt = 0; mt < 2; ++mt)
          acc[mt][nt] = __builtin_amdgcn_mfma_f32_16x16x32_bf16(a[mt], b, acc[mt][nt], 0, 0, 0);
      }
    }
  }

  float* ob = out + (size_t)t * 64 * 65536;
  float bias[2][4];
  #pragma unroll
  for (int mt = 0; mt < 2; ++mt)
    #pragma unroll
    for (int r = 0; r < 4; ++r) bias[mt][r] = bo[wm * 32 + mt * 16 + lg * 4 + r];
  #pragma unroll
  for (int mt = 0; mt < 2; ++mt)
    #pragma unroll
    for (int nt = 0; nt < 4; ++nt) {
      int ty = wn * 4 + nt;
      bf16x4 resv = *(const bf16x4*)&yp[((ty + 1) * 18 + l15 + 1) * 76 + wm * 32 + mt * 16 + lg * 4];
      #pragma unroll
      for (int r = 0; r < 4; ++r) {
        int co = wm * 32 + mt * 16 + lg * 4 + r;
        float res = b2f((unsigned short)resv[r]);
        ob[(size_t)co * 65536 + (size_t)(y0 + ty) * 256 + x0 + l15] = res + acc[mt][nt][r] + bias[mt][r];
      }
    }
}

// ---------------- launcher ----------------
extern "C" void kernel_launch(void* const* d_in, const int* in_sizes, int n_in,
                              void* d_out, int out_size, void* d_ws, size_t ws_size,
                              hipStream_t stream) {
  const float* x  = (const float*)d_in[0];
  const float* Wq = (const float*)d_in[1];
  const float* bq = (const float*)d_in[2];
  const float* Wk = (const float*)d_in[3];
  const float* bk = (const float*)d_in[4];
  const float* Wv = (const float*)d_in[5];
  const float* bv = (const float*)d_in[6];
  const float* Wo = (const float*)d_in[7];
  const float* bo = (const float*)d_in[8];
  float* out = (float*)d_out;

  char* ws = (char*)d_ws;
  bf16* wt  = (bf16*)(ws + 0);
  bf16* wot = (bf16*)(ws + 110592);
  bf16* q   = (bf16*)(ws + 262144);              // reused as y_img after qk_gemm
  bf16* k   = (bf16*)(ws + 67371008);
  float2* pstats = (float2*)(ws + 67371008);     // overlaps k (dead after qk_gemm)
  bf16* S   = (bf16*)(ws + 134479872);
  bf16* vt  = (bf16*)(ws + 268697600);
  bf16* y   = (bf16*)(ws + 262144);              // channels-last [8][256][256][64]
  bf16* v   = S;                                 // v staged where S will go (dead before qk)
  // requires ws_size >= 335,806,464 bytes

  prep_w<<<216, 256, 0, stream>>>(Wq, Wk, Wv, Wo, wt, wot);
  qkv_conv<<<4096, 256, 0, stream>>>(x, wt, bq, bk, bv, q, k, v);
  transpose_v<<<8192, 256, 0, stream>>>(v, vt);
  qk_gemm<<<1024, 512, 0, stream>>>(q, k, S);
  row_stats<<<16384, 256, 0, stream>>>(S, pstats);
  pv_gemm<<<512, 512, 0, stream>>>(S, vt, pstats, y);
  out_conv<<<2048, 512, 0, stream>>>(y, wot, bo, out);
}

// Round 17
// 397.694 us; speedup vs baseline: 1.1171x; 1.0929x over previous
//
#include <hip/hip_runtime.h>
#include <hip/hip_bf16.h>
#include <stdint.h>

// Spatial local attention, MI355X bf16-MFMA implementation.
// Round 17: out_conv stages wot into LDS (XOR-swizzled, 72KB) -- removes 36 serial
// L2-latency global a-loads from the MFMA chain. Everything else = round 16.
//
// Workspace layout (bytes), total = 335,806,464 (~320.3 MiB):
//   [0        , 110592   ) Wqkv_t bf16 [9][192][32]
//   [110592   , 184320   ) Wo_t   bf16 [9][64][64]
//   [262144   , 67371008 ) q  bf16 [64][1024][512]   (d''-ordered; reused as y_img)
//   [67371008 , 134479872) k  bf16 [64][1024][512]   (pstats overlays after qk)
//   [134479872, 268697600) S   bf16 [64][1024][1024] (raw scaled scores)
//   [268697600, 335806464) vt bf16 [64][512][1024]   (rows = d' = pyix*8+jj)

using bf16 = __hip_bfloat16;
typedef short bf16x8 __attribute__((ext_vector_type(8)));
typedef short bf16x4 __attribute__((ext_vector_type(4)));
typedef float f32x4 __attribute__((ext_vector_type(4)));

#define AS1 __attribute__((address_space(1)))
#define AS3 __attribute__((address_space(3)))

__device__ __forceinline__ void gload_lds16(const void* g, void* l) {
  __builtin_amdgcn_global_load_lds((const AS1 unsigned int*)g, (AS3 unsigned int*)l, 16, 0, 0);
}
__device__ __forceinline__ float b2f(unsigned short u) {
  union { unsigned int i; float f; } x; x.i = ((unsigned)u) << 16; return x.f;
}
__device__ __forceinline__ unsigned short f2b(float f) {
  __hip_bfloat16 h = __float2bfloat16(f);
  return *reinterpret_cast<unsigned short*>(&h);
}

// ---------------- weight prep: f32 OIHW -> bf16 [step][co][ci] ----------------
__global__ __launch_bounds__(256) void prep_w(const float* __restrict__ Wq, const float* __restrict__ Wk,
                                              const float* __restrict__ Wv, const float* __restrict__ Wo,
                                              bf16* __restrict__ wt, bf16* __restrict__ wot) {
  int i = blockIdx.x * 256 + threadIdx.x;
  if (i < 9 * 192 * 32) {              // wt[s][co192][ci]
    int ci = i & 31, co192 = (i >> 5) % 192, s = i / 6144;
    int dy = s / 3, dx = s % 3;
    int proj = co192 >> 6, co = co192 & 63;
    const float* Ws = (proj == 0) ? Wq : ((proj == 1) ? Wk : Wv);
    wt[i] = __float2bfloat16(Ws[((co * 32 + ci) * 3 + dy) * 3 + dx]);
  }
  if (i < 9 * 64 * 64) {               // wot[s][co][ci]
    int ci = i & 63, co = (i >> 6) & 63, s = i >> 12;
    wot[i] = __float2bfloat16(Wo[((co * 64 + ci) * 3 + (s / 3)) * 3 + (s % 3)]);
  }
}

// ---------------- QKV windowed conv: direct d''-ordered stores ----------------
__global__ __launch_bounds__(256) void qkv_conv(const float* __restrict__ x, const bf16* __restrict__ wt,
                                                const float* __restrict__ bq, const float* __restrict__ bk,
                                                const float* __restrict__ bv,
                                                bf16* __restrict__ qout, bf16* __restrict__ kout,
                                                bf16* __restrict__ vout) {
  __shared__ bf16 xp[8000];            // [win][py*10+px][ci pad40], 16 KB
  int tid = threadIdx.x, bid = blockIdx.x;
  int t = bid >> 9, g = bid & 511;
  int gy = g >> 4, gx0 = (g & 15) * 2;

  unsigned int* xp32 = (unsigned int*)xp;
  for (int i = tid; i < 4000; i += 256) xp32[i] = 0u;
  __syncthreads();
  const float* xb = x + (size_t)t * 32 * 65536;
  #pragma unroll
  for (int it = 0; it < 16; ++it) {
    int e = tid + it * 256;
    int ix = e & 7, win = (e >> 3) & 1, iy = (e >> 4) & 7, ci = e >> 7;
    float val = xb[(size_t)ci * 65536 + (gy * 8 + iy) * 256 + (gx0 + win) * 8 + ix];
    xp[(win * 100 + (iy + 1) * 10 + (ix + 1)) * 40 + ci] = __float2bfloat16(val);
  }
  __syncthreads();

  int wv = tid >> 6, l = tid & 63, l15 = l & 15, lg = l >> 4;
  f32x4 z4 = {0.f, 0.f, 0.f, 0.f};
  f32x4 acc[3][8];
  for (int i = 0; i < 3; ++i) for (int j = 0; j < 8; ++j) acc[i][j] = z4;

  #pragma unroll
  for (int s = 0; s < 9; ++s) {
    const int dy = s / 3, dx = s % 3;
    bf16x8 a[3];
    #pragma unroll
    for (int mt = 0; mt < 3; ++mt)
      a[mt] = *(const bf16x8*)&wt[((size_t)s * 192 + wv * 48 + mt * 16 + l15) * 32 + lg * 8];
    #pragma unroll
    for (int nt = 0; nt < 8; ++nt) {
      int n = nt * 16 + l15;
      int win = n >> 6, px = n & 63;
      int iy = px >> 3, ix = px & 7;
      bf16x8 b = *(const bf16x8*)&xp[(win * 100 + (iy + dy) * 10 + (ix + dx)) * 40 + lg * 8];
      #pragma unroll
      for (int mt = 0; mt < 3; ++mt)
        acc[mt][nt] = __builtin_amdgcn_mfma_f32_16x16x32_bf16(a[mt], b, acc[mt][nt], 0, 0, 0);
    }
  }

  #pragma unroll
  for (int mt = 0; mt < 3; ++mt) {
    int c0 = wv * 48 + mt * 16 + lg * 4;
    int proj = c0 >> 6;
    int co0 = c0 & 63;
    int head = co0 >> 3, jj0 = co0 & 7;
    const float* bptr = (proj == 0) ? bq : ((proj == 1) ? bk : bv);
    bf16* dst = (proj == 0) ? qout : ((proj == 1) ? kout : vout);
    float bias[4];
    #pragma unroll
    for (int r = 0; r < 4; ++r) bias[r] = bptr[co0 + r];
    size_t bh = (size_t)(t * 8 + head);
    #pragma unroll
    for (int nt = 0; nt < 8; ++nt) {
      int n = nt * 16 + l15;
      int win2 = n >> 6, pyix = n & 63;
      size_t gwin = (size_t)gy * 32 + gx0 + win2;
      bf16x4 pack;
      #pragma unroll
      for (int r = 0; r < 4; ++r) pack[r] = (short)f2b(acc[mt][nt][r] + bias[r]);
      *(bf16x4*)&dst[(bh * 1024 + gwin) * 512 + pyix * 8 + jj0] = pack;
    }
  }
}

// ---------------- V transpose (plain): [bh][win][d''] -> [bh][d''][win] ----------------
__global__ __launch_bounds__(256) void transpose_v(const bf16* __restrict__ v, bf16* __restrict__ vt) {
  __shared__ bf16 tl[64 * 72];         // [d_local][win pad72]
  int tid = threadIdx.x, bid = blockIdx.x;
  int bh = bid >> 7, wtile = (bid >> 3) & 15, dtile = bid & 7;
  int w0 = wtile * 64, d0 = dtile * 64;
  const bf16* vb = v + ((size_t)bh * 1024 + w0) * 512 + d0;
  int win_l = tid >> 2, dseg = (tid & 3) * 16;
  bf16x8 x0 = *(const bf16x8*)&vb[(size_t)win_l * 512 + dseg];
  bf16x8 x1 = *(const bf16x8*)&vb[(size_t)win_l * 512 + dseg + 8];
  #pragma unroll
  for (int j = 0; j < 8; ++j) {
    *(short*)&tl[(dseg + j) * 72 + win_l] = x0[j];
    *(short*)&tl[(dseg + 8 + j) * 72 + win_l] = x1[j];
  }
  __syncthreads();
  int d_l = tid >> 2, wseg = (tid & 3) * 16;
  bf16x8 y0 = *(const bf16x8*)&tl[d_l * 72 + wseg];
  bf16x8 y1 = *(const bf16x8*)&tl[d_l * 72 + wseg + 8];
  bf16* vtb = vt + ((size_t)bh * 512 + d0 + d_l) * 1024 + w0 + wseg;
  *(bf16x8*)&vtb[0] = y0;
  *(bf16x8*)&vtb[8] = y1;
}

// ---------------- batched QK^T -> S bf16: counted-vmcnt, A-dbuf + B-ring3 ----------------
__global__ __launch_bounds__(512, 1) void qk_gemm(const bf16* __restrict__ q, const bf16* __restrict__ k,
                                                  bf16* __restrict__ S) {
  __shared__ bf16 smem[81920];         // 160 KiB
  int tid = threadIdx.x;
  int bid = (blockIdx.x & 7) * 128 + (blockIdx.x >> 3);    // XCD swizzle (1024 % 8 == 0)
  int batch = bid >> 4, tm = (bid >> 2) & 3, tn = bid & 3;
  const bf16* Qb = q + (size_t)batch * 1024 * 512 + (size_t)tm * 256 * 512;
  const bf16* Kb = k + (size_t)batch * 1024 * 512 + (size_t)tn * 256 * 512;
  int w = tid >> 6, l = tid & 63, l15 = l & 15, lg = l >> 4;
  int wm2 = w >> 2, wn4 = w & 3;
  int lr = l >> 3, sl = (l & 7) ^ lr, swz = l15 & 7;
  f32x4 z4 = {0.f, 0.f, 0.f, 0.f};
  f32x4 acc[8][4];
  for (int i = 0; i < 8; ++i) for (int j = 0; j < 4; ++j) acc[i][j] = z4;

  #define QK_STG_A(T)                                                            \
    { char* base = (char*)smem + ((T) & 1) * 32768;                              \
      _Pragma("unroll")                                                          \
      for (int p = 0; p < 4; ++p) {                                              \
        int row = p * 64 + w * 8 + lr;                                           \
        gload_lds16(Qb + (size_t)row * 512 + (T) * 64 + sl * 8,                  \
                    base + p * 8192 + w * 1024); } }
  #define QK_STG_B(T)                                                            \
    { char* base = (char*)smem + 65536 + ((T) % 3) * 32768;                      \
      _Pragma("unroll")                                                          \
      for (int p = 0; p < 4; ++p) {                                              \
        int row = p * 64 + w * 8 + lr;                                           \
        gload_lds16(Kb + (size_t)row * 512 + (T) * 64 + sl * 8,                  \
                    base + p * 8192 + w * 1024); } }

  QK_STG_B(0); QK_STG_A(0); QK_STG_B(1);
  asm volatile("s_waitcnt vmcnt(4)" ::: "memory");
  __builtin_amdgcn_s_barrier();
  __builtin_amdgcn_sched_barrier(0);

  #pragma unroll
  for (int t = 0; t < 8; ++t) {
    if (t + 1 < 8) QK_STG_A(t + 1);
    if (t + 2 < 8) QK_STG_B(t + 2);
    const bf16* At = (const bf16*)((char*)smem + (t & 1) * 32768);
    const bf16* Bt = (const bf16*)((char*)smem + 65536 + (t % 3) * 32768);
    __builtin_amdgcn_s_setprio(1);
    #pragma unroll
    for (int kk = 0; kk < 2; ++kk) {
      int ps = (kk * 4 + lg) ^ swz;
      bf16x8 a[8], b[4];
      #pragma unroll
      for (int i = 0; i < 8; ++i)
        a[i] = *(const bf16x8*)&At[(wm2 * 128 + i * 16 + l15) * 64 + ps * 8];
      #pragma unroll
      for (int j = 0; j < 4; ++j)
        b[j] = *(const bf16x8*)&Bt[(wn4 * 64 + j * 16 + l15) * 64 + ps * 8];
      #pragma unroll
      for (int i = 0; i < 8; ++i)
        #pragma unroll
        for (int j = 0; j < 4; ++j)
          acc[i][j] = __builtin_amdgcn_mfma_f32_16x16x32_bf16(a[i], b[j], acc[i][j], 0, 0, 0);
    }
    __builtin_amdgcn_s_setprio(0);
    if (t + 2 < 8)      { asm volatile("s_waitcnt vmcnt(4)" ::: "memory"); }
    else if (t + 1 < 8) { asm volatile("s_waitcnt vmcnt(0)" ::: "memory"); }
    __builtin_amdgcn_s_barrier();
    __builtin_amdgcn_sched_barrier(0);
  }
  #undef QK_STG_A
  #undef QK_STG_B

  const float SCALE = 0.04419417382415922f;  // 1/sqrt(512)
  bf16* Sb = S + (size_t)batch * 1024 * 1024;
  #pragma unroll
  for (int i = 0; i < 8; ++i)
    #pragma unroll
    for (int j = 0; j < 4; ++j)
      #pragma unroll
      for (int r = 0; r < 4; ++r) {
        int row = tm * 256 + wm2 * 128 + i * 16 + lg * 4 + r;
        int col = tn * 256 + wn4 * 64 + j * 16 + l15;
        Sb[(size_t)row * 1024 + col] = __float2bfloat16(acc[i][j][r] * SCALE);
      }
}

// ---------------- row stats: per row m = max, rcp = 1/sum(exp(s-m)) ----------------
__global__ __launch_bounds__(256) void row_stats(const bf16* __restrict__ S, float2* __restrict__ pstats) {
  int l = threadIdx.x & 63;
  size_t row = (size_t)blockIdx.x * 4 + (threadIdx.x >> 6);
  const bf16* p = S + row * 1024 + l * 16;
  bf16x8 s0 = *(const bf16x8*)p;
  bf16x8 s1 = *(const bf16x8*)(p + 8);
  float f[16];
  #pragma unroll
  for (int i = 0; i < 8; ++i) { f[i] = b2f((unsigned short)s0[i]); f[8 + i] = b2f((unsigned short)s1[i]); }
  float m = f[0];
  #pragma unroll
  for (int i = 1; i < 16; ++i) m = fmaxf(m, f[i]);
  for (int d = 1; d < 64; d <<= 1) m = fmaxf(m, __shfl_xor(m, d));
  float sum = 0.f;
  #pragma unroll
  for (int i = 0; i < 16; ++i) sum += __expf(f[i] - m);
  for (int d = 1; d < 64; d <<= 1) sum += __shfl_xor(sum, d);
  if (l == 0) {
    float2 st; st.x = m; st.y = 1.0f / sum;
    pstats[row] = st;
  }
}

// ---------------- batched PV: counted-vmcnt, A(exp)-dbuf + B-ring3 (round-14) ----------------
__global__ __launch_bounds__(512, 1) void pv_gemm(const bf16* __restrict__ S, const bf16* __restrict__ vt,
                                                  const float2* __restrict__ pstats,
                                                  bf16* __restrict__ y) {
  __shared__ bf16 smem[81920];         // 160 KiB: A buf c at c*32768 B; B slot s at 65536+s*32768 B
  int tid = threadIdx.x;
  int bid = (blockIdx.x & 7) * 64 + (blockIdx.x >> 3);     // XCD swizzle (512 % 8 == 0)
  int batch = bid >> 3, bq = (bid >> 1) & 3, bd = bid & 1;
  const bf16* Pb = S + (size_t)batch * 1024 * 1024 + (size_t)bq * 256 * 1024;
  const bf16* Vb = vt + (size_t)batch * 512 * 1024 + (size_t)bd * 256 * 1024;
  int w = tid >> 6, l = tid & 63, l15 = l & 15, lg = l >> 4;
  int wm2 = w >> 2, wn4 = w & 3;
  int lr = l >> 3, sl = (l & 7) ^ lr, swz = l15 & 7;
  f32x4 z4 = {0.f, 0.f, 0.f, 0.f};
  f32x4 acc[8][4];
  for (int i = 0; i < 8; ++i) for (int j = 0; j < 4; ++j) acc[i][j] = z4;

  float m4[4], r4[4];
  #pragma unroll
  for (int p = 0; p < 4; ++p) {
    float2 st = pstats[(size_t)batch * 1024 + bq * 256 + p * 64 + w * 8 + lr];
    m4[p] = st.x; r4[p] = st.y;
  }

  bf16x8 areg[4];
  #define PV_ISSUE_A(tt)                                                          \
    { _Pragma("unroll")                                                           \
      for (int p = 0; p < 4; ++p)                                                 \
        areg[p] = *(const bf16x8*)&Pb[(size_t)(p * 64 + w * 8 + lr) * 1024 +      \
                                      (tt) * 64 + sl * 8]; }
  #define PV_STG_B(T)                                                             \
    { char* base = (char*)smem + 65536 + ((T) % 3) * 32768;                       \
      _Pragma("unroll")                                                           \
      for (int p = 0; p < 4; ++p) {                                               \
        int row = p * 64 + w * 8 + lr;                                            \
        gload_lds16(Vb + (size_t)row * 1024 + (T) * 64 + sl * 8,                  \
                    base + p * 8192 + w * 1024); } }
  #define PV_WRITE_A(buf)                                                         \
    { char* base = (char*)smem + (buf) * 32768;                                   \
      _Pragma("unroll")                                                           \
      for (int p = 0; p < 4; ++p) {                                               \
        bf16x8 o;                                                                 \
        _Pragma("unroll")                                                         \
        for (int e = 0; e < 8; ++e) {                                             \
          float fv = b2f((unsigned short)areg[p][e]);                             \
          o[e] = (short)f2b(__expf(fv - m4[p]) * r4[p]);                          \
        }                                                                         \
        *(bf16x8*)(base + p * 8192 + w * 1024 + l * 16) = o; }                    \
    }

  // prologue: B0, A0(regs), B1 (oldest first); vmcnt(4) drains B0+A0; transform A0.
  PV_STG_B(0); PV_ISSUE_A(0); PV_STG_B(1);
  asm volatile("s_waitcnt vmcnt(4)" ::: "memory");
  PV_WRITE_A(0);
  asm volatile("s_waitcnt lgkmcnt(0)" ::: "memory");
  __builtin_amdgcn_s_barrier();
  __builtin_amdgcn_sched_barrier(0);

  #pragma unroll
  for (int t = 0; t < 16; ++t) {
    if (t + 1 < 16) PV_ISSUE_A(t + 1);
    if (t + 2 < 16) PV_STG_B(t + 2);
    const bf16* At = (const bf16*)((char*)smem + (t & 1) * 32768);
    const bf16* Bt = (const bf16*)((char*)smem + 65536 + (t % 3) * 32768);
    __builtin_amdgcn_s_setprio(1);
    #pragma unroll
    for (int kk = 0; kk < 2; ++kk) {
      int ps = (kk * 4 + lg) ^ swz;
      bf16x8 a[8], b[4];
      #pragma unroll
      for (int i = 0; i < 8; ++i)
        a[i] = *(const bf16x8*)&At[(wm2 * 128 + i * 16 + l15) * 64 + ps * 8];
      #pragma unroll
      for (int j = 0; j < 4; ++j)
        b[j] = *(const bf16x8*)&Bt[(wn4 * 64 + j * 16 + l15) * 64 + ps * 8];
      #pragma unroll
      for (int i = 0; i < 8; ++i)
        #pragma unroll
        for (int j = 0; j < 4; ++j)
          acc[i][j] = __builtin_amdgcn_mfma_f32_16x16x32_bf16(a[i], b[j], acc[i][j], 0, 0, 0);
    }
    __builtin_amdgcn_s_setprio(0);
    if (t + 2 < 16)      { asm volatile("s_waitcnt vmcnt(4)" ::: "memory"); }
    else if (t + 1 < 16) { asm volatile("s_waitcnt vmcnt(0)" ::: "memory"); }
    if (t + 1 < 16) PV_WRITE_A((t + 1) & 1);
    asm volatile("s_waitcnt lgkmcnt(0)" ::: "memory");
    __builtin_amdgcn_s_barrier();
    __builtin_amdgcn_sched_barrier(0);
  }
  #undef PV_ISSUE_A
  #undef PV_STG_B
  #undef PV_WRITE_A

  // epilogue: direct channels-last stores (16B runs per 8 lanes)
  int t2 = batch >> 3, h = batch & 7;
  #pragma unroll
  for (int i = 0; i < 8; ++i)
    #pragma unroll
    for (int j = 0; j < 4; ++j)
      #pragma unroll
      for (int r = 0; r < 4; ++r) {
        int win = bq * 256 + wm2 * 128 + i * 16 + lg * 4 + r;
        int dp = bd * 256 + wn4 * 64 + j * 16 + l15;
        int jj = dp & 7, pyix = dp >> 3;
        int gy = win >> 5, gx = win & 31;
        int Y = gy * 8 + (pyix >> 3), X = gx * 8 + (pyix & 7);
        y[(((size_t)t2 * 256 + Y) * 256 + X) * 64 + h * 8 + jj] = __float2bfloat16(acc[i][j][r]);
      }
}

// ---------------- final full-image conv + residual -> f32 out (8 waves, wot in LDS) ----------------
// LDS: yp [324][76] (49248 B) + wotl [576][64] XOR-swizzled (73728 B) = 122976 B.
// wotl phys slot = logical ^ (row&7); read row&7 == l15&7 -> 2-way banks (free).
__global__ __launch_bounds__(512) void out_conv(const bf16* __restrict__ yimg, const bf16* __restrict__ wot,
                                                const float* __restrict__ bo, float* __restrict__ out) {
  __shared__ bf16 yp[324 * 76];        // [py*18+px][ci pad76]
  __shared__ bf16 wotl[576 * 64];      // [s*64+co][ci], slot-swizzled
  int tid = threadIdx.x, bid = blockIdx.x;
  int t = bid >> 8, tile = bid & 255;
  int y0 = (tile >> 4) * 16, x0 = (tile & 15) * 16;
  const bf16* yb = yimg + (size_t)t * 256 * 256 * 64;

  // stage wot -> LDS: 4608 16B chunks, pre-swizzled source, linear dest
  #pragma unroll
  for (int i = 0; i < 9; ++i) {
    int c = tid + i * 512;             // chunk id: row = c>>3, phys slot = c&7
    int row = c >> 3, sl0 = c & 7;
    gload_lds16(wot + (size_t)row * 64 + (sl0 ^ (row & 7)) * 8,
                (char*)wotl + (size_t)(tid & 63) * 16 + (tid >> 6) * 1024 + i * 8192);
  }
  for (int e = tid; e < 324 * 8; e += 512) {
    int seg = e & 7, pos = e >> 3;
    int ppx = pos % 18, ppy = pos / 18;
    int gy = y0 + ppy - 1, gx = x0 + ppx - 1;
    bf16x8 val = {0, 0, 0, 0, 0, 0, 0, 0};
    if ((unsigned)gy < 256u && (unsigned)gx < 256u)
      val = *(const bf16x8*)&yb[((size_t)gy * 256 + gx) * 64 + seg * 8];
    *(bf16x8*)&yp[pos * 76 + seg * 8] = val;
  }
  __syncthreads();

  int w = tid >> 6, l = tid & 63, l15 = l & 15, lg = l >> 4;
  int wm = w & 1, wn = w >> 1;         // wn 0..3: 4 ty rows each
  f32x4 z4 = {0.f, 0.f, 0.f, 0.f};
  f32x4 acc[2][4];
  for (int i = 0; i < 2; ++i) for (int j = 0; j < 4; ++j) acc[i][j] = z4;

  #pragma unroll
  for (int s9 = 0; s9 < 9; ++s9) {
    const int dy = s9 / 3, dx = s9 % 3;
    #pragma unroll
    for (int half = 0; half < 2; ++half) {
      bf16x8 a[2];
      #pragma unroll
      for (int mt = 0; mt < 2; ++mt) {
        int arow = s9 * 64 + wm * 32 + mt * 16 + l15;
        int ps = (half * 4 + lg) ^ (arow & 7);
        a[mt] = *(const bf16x8*)&wotl[arow * 64 + ps * 8];
      }
      #pragma unroll
      for (int nt = 0; nt < 4; ++nt) {
        int ty = wn * 4 + nt;
        bf16x8 b = *(const bf16x8*)&yp[((ty + dy) * 18 + l15 + dx) * 76 + half * 32 + lg * 8];
        #pragma unroll
        for (int mt = 0; mt < 2; ++mt)
          acc[mt][nt] = __builtin_amdgcn_mfma_f32_16x16x32_bf16(a[mt], b, acc[mt][nt], 0, 0, 0);
      }
    }
  }

  float* ob = out + (size_t)t * 64 * 65536;
  float bias[2][4];
  #pragma unroll
  for (int mt = 0; mt < 2; ++mt)
    #pragma unroll
    for (int r = 0; r < 4; ++r) bias[mt][r] = bo[wm * 32 + mt * 16 + lg * 4 + r];
  #pragma unroll
  for (int mt = 0; mt < 2; ++mt)
    #pragma unroll
    for (int nt = 0; nt < 4; ++nt) {
      int ty = wn * 4 + nt;
      bf16x4 resv = *(const bf16x4*)&yp[((ty + 1) * 18 + l15 + 1) * 76 + wm * 32 + mt * 16 + lg * 4];
      #pragma unroll
      for (int r = 0; r < 4; ++r) {
        int co = wm * 32 + mt * 16 + lg * 4 + r;
        float res = b2f((unsigned short)resv[r]);
        ob[(size_t)co * 65536 + (size_t)(y0 + ty) * 256 + x0 + l15] = res + acc[mt][nt][r] + bias[mt][r];
      }
    }
}

// ---------------- launcher ----------------
extern "C" void kernel_launch(void* const* d_in, const int* in_sizes, int n_in,
                              void* d_out, int out_size, void* d_ws, size_t ws_size,
                              hipStream_t stream) {
  const float* x  = (const float*)d_in[0];
  const float* Wq = (const float*)d_in[1];
  const float* bq = (const float*)d_in[2];
  const float* Wk = (const float*)d_in[3];
  const float* bk = (const float*)d_in[4];
  const float* Wv = (const float*)d_in[5];
  const float* bv = (const float*)d_in[6];
  const float* Wo = (const float*)d_in[7];
  const float* bo = (const float*)d_in[8];
  float* out = (float*)d_out;

  char* ws = (char*)d_ws;
  bf16* wt  = (bf16*)(ws + 0);
  bf16* wot = (bf16*)(ws + 110592);
  bf16* q   = (bf16*)(ws + 262144);              // reused as y_img after qk_gemm
  bf16* k   = (bf16*)(ws + 67371008);
  float2* pstats = (float2*)(ws + 67371008);     // overlaps k (dead after qk_gemm)
  bf16* S   = (bf16*)(ws + 134479872);
  bf16* vt  = (bf16*)(ws + 268697600);
  bf16* y   = (bf16*)(ws + 262144);              // channels-last [8][256][256][64]
  bf16* v   = S;                                 // v staged where S will go (dead before qk)
  // requires ws_size >= 335,806,464 bytes

  prep_w<<<216, 256, 0, stream>>>(Wq, Wk, Wv, Wo, wt, wot);
  qkv_conv<<<4096, 256, 0, stream>>>(x, wt, bq, bk, bv, q, k, v);
  transpose_v<<<8192, 256, 0, stream>>>(v, vt);
  qk_gemm<<<1024, 512, 0, stream>>>(q, k, S);
  row_stats<<<16384, 256, 0, stream>>>(S, pstats);
  pv_gemm<<<512, 512, 0, stream>>>(S, vt, pstats, y);
  out_conv<<<2048, 512, 0, stream>>>(y, wot, bo, out);
}